// Round 1
// 471.260 us; speedup vs baseline: 1.4748x; 1.4748x over previous
//
#include <hip/hip_runtime.h>
#include <hip/hip_bf16.h>

#define TOK 8192      // B*S tokens
#define HD 2048       // hidden
#define NE 8          // experts
#define KTOP 2
#define NSLOT (TOK * KTOP)
#define NCHUNK (TOK / 256)   // 32 routing chunks

typedef __attribute__((ext_vector_type(8))) short bf16x8;
typedef __attribute__((ext_vector_type(4))) float f32x4;

// async global->LDS, 16B per lane, dest = wave-uniform base + lane*16
#define GLDS16(g, l) __builtin_amdgcn_global_load_lds( \
    (const __attribute__((address_space(1))) void*)(g), \
    (__attribute__((address_space(3))) void*)(l), 16, 0, 0)

// round-to-nearest-even fp32 -> bf16 bits
__device__ __forceinline__ unsigned short f2bf(float f) {
  union { float f; unsigned u; } v; v.f = f;
  unsigned r = v.u + 0x7fffu + ((v.u >> 16) & 1u);
  return (unsigned short)(r >> 16);
}
__device__ __forceinline__ float bf2f(unsigned short b) {
  union { unsigned u; float f; } v; v.u = ((unsigned)b) << 16;
  return v.f;
}

// ---------------- fused: x->bf16 + router (logits, softmax, top-2) ----------------
// one block per token; x staged in LDS so Wg reads are coalesced (k = tid + i*256)
// NO global atomics: counts are reconstructed by hist/scan/assign below.
__global__ __launch_bounds__(256) void routex_kernel(
    const float* __restrict__ x, const float* __restrict__ Wg, const float* __restrict__ bg,
    int* __restrict__ eidx2, float* __restrict__ gate2,
    unsigned short* __restrict__ xbf) {
  __shared__ float xs[HD];     // 8 KB
  __shared__ float red[4][NE];
  int t = blockIdx.x;
  int tid = threadIdx.x;
  const float4* xr = (const float4*)(x + (size_t)t * HD);
  float4 a = xr[tid * 2], b = xr[tid * 2 + 1];
  union { bf16x8 v; unsigned short s[8]; } o;
  o.s[0] = f2bf(a.x); o.s[1] = f2bf(a.y); o.s[2] = f2bf(a.z); o.s[3] = f2bf(a.w);
  o.s[4] = f2bf(b.x); o.s[5] = f2bf(b.y); o.s[6] = f2bf(b.z); o.s[7] = f2bf(b.w);
  *(bf16x8*)(xbf + (size_t)t * HD + tid * 8) = o.v;
  *(float4*)(xs + tid * 8) = a;
  *(float4*)(xs + tid * 8 + 4) = b;
  __syncthreads();

  float acc[NE];
#pragma unroll
  for (int e = 0; e < NE; e++) acc[e] = 0.f;
#pragma unroll
  for (int i = 0; i < HD / 256; i++) {
    int k = tid + i * 256;               // consecutive lanes -> consecutive Wg rows
    float v = xs[k];
    const float4* wr = (const float4*)(Wg + (size_t)k * NE);
    float4 w0 = wr[0], w1 = wr[1];
    acc[0] += v * w0.x; acc[1] += v * w0.y; acc[2] += v * w0.z; acc[3] += v * w0.w;
    acc[4] += v * w1.x; acc[5] += v * w1.y; acc[6] += v * w1.z; acc[7] += v * w1.w;
  }
#pragma unroll
  for (int e = 0; e < NE; e++) {
    float v = acc[e];
#pragma unroll
    for (int s = 32; s > 0; s >>= 1) v += __shfl_xor(v, s, 64);
    acc[e] = v;
  }
  int lane = tid & 63, w = tid >> 6;
  if (lane == 0)
#pragma unroll
    for (int e = 0; e < NE; e++) red[w][e] = acc[e];
  __syncthreads();
  if (tid == 0) {
    float lg[NE];
#pragma unroll
    for (int e = 0; e < NE; e++)
      lg[e] = red[0][e] + red[1][e] + red[2][e] + red[3][e] + bg[e];
    float m = lg[0];
#pragma unroll
    for (int e = 1; e < NE; e++) m = fmaxf(m, lg[e]);
    float p[NE], d = 0.f;
#pragma unroll
    for (int e = 0; e < NE; e++) { p[e] = __expf(lg[e] - m); d += p[e]; }
    float inv = 1.f / d;
    int b0 = 0;
#pragma unroll
    for (int e = 1; e < NE; e++) if (lg[e] > lg[b0]) b0 = e;
    int b1 = (b0 == 0) ? 1 : 0;
#pragma unroll
    for (int e = 0; e < NE; e++) if (e != b0 && lg[e] > lg[b1]) b1 = e;
    eidx2[t * 2 + 0] = b0; gate2[t * 2 + 0] = p[b0] * inv;
    eidx2[t * 2 + 1] = b1; gate2[t * 2 + 1] = p[b1] * inv;
  }
}

// ---------------- per-chunk expert histogram (ballot-based, no atomics) ----------------
__global__ __launch_bounds__(256) void hist_kernel(const int* __restrict__ eidx2,
                                                   int* __restrict__ hist) {
  __shared__ int h[4][NE];
  int b = blockIdx.x, tid = threadIdx.x;
  int lane = tid & 63, w = tid >> 6;
  int t = b * 256 + tid;
  int e0 = eidx2[t * 2], e1 = eidx2[t * 2 + 1];
#pragma unroll
  for (int ee = 0; ee < NE; ee++) {
    unsigned long long m0 = __ballot(e0 == ee);
    unsigned long long m1 = __ballot(e1 == ee);
    if (lane == 0) h[w][ee] = __popcll(m0) + __popcll(m1);
  }
  __syncthreads();
  if (tid < NE) hist[b * NE + tid] = h[0][tid] + h[1][tid] + h[2][tid] + h[3][tid];
}

// ---------------- scan: expert totals + expert offsets + per-chunk bases ----------------
__global__ void scan_kernel(const int* __restrict__ hist, int* __restrict__ cnt,
                            int* __restrict__ chunk_base) {
  __shared__ int run[NE];
  __shared__ int off[NE];
  __shared__ int cb[NCHUNK][NE];
  int tid = threadIdx.x;   // 64 threads
  if (tid < NE) {
    int s = 0;
    for (int b = 0; b < NCHUNK; b++) { cb[b][tid] = s; s += hist[b * NE + tid]; }
    run[tid] = s;
    cnt[tid] = s;
  }
  __syncthreads();
  if (tid == 0) {
    int s = 0;
    for (int e = 0; e < NE; e++) { off[e] = s; s += run[e]; }
  }
  __syncthreads();
  for (int i = tid; i < NCHUNK * NE; i += 64) {
    int b = i / NE, e = i % NE;
    chunk_base[i] = cb[b][e] + off[e];
  }
}

// ---------------- assign: deterministic compacted slot lists (ballot rank, no atomics) ----
__global__ __launch_bounds__(256) void assign_kernel(
    const int* __restrict__ eidx2, const float* __restrict__ gate2,
    const int* __restrict__ chunk_base,
    int* __restrict__ slot_tok, float* __restrict__ slot_gate, int* __restrict__ tok_slot) {
  __shared__ int wcnt[2][4][NE];   // [item j][wave][expert]
  __shared__ int cbase[NE];
  int b = blockIdx.x;
  int tid = threadIdx.x;
  int lane = tid & 63, w = tid >> 6;
  if (tid < NE) cbase[tid] = chunk_base[b * NE + tid];
  int t = b * 256 + tid;
  int e0 = eidx2[t * 2], e1 = eidx2[t * 2 + 1];
  unsigned long long lt = (1ull << lane) - 1ull;
  int r0 = 0, r1 = 0;
#pragma unroll
  for (int ee = 0; ee < NE; ee++) {
    unsigned long long m0 = __ballot(e0 == ee);
    unsigned long long m1 = __ballot(e1 == ee);
    if (e0 == ee) r0 = __popcll(m0 & lt);
    if (e1 == ee) r1 = __popcll(m1 & lt);
    if (lane == 0) { wcnt[0][w][ee] = __popcll(m0); wcnt[1][w][ee] = __popcll(m1); }
  }
  __syncthreads();
  // base for item (j, wave w): sum of wcnt over (j',w') pairs ordered before it
  int base0 = 0, base1 = 0;
#pragma unroll
  for (int p = 0; p < 8; p++) {
    int c0 = wcnt[p >> 2][p & 3][e0];
    int c1 = wcnt[p >> 2][p & 3][e1];
    if (p < w) base0 += c0;
    if (p < 4 + w) base1 += c1;
  }
  int s0 = cbase[e0] + base0 + r0;
  int s1 = cbase[e1] + base1 + r1;
  slot_tok[s0] = t; slot_gate[s0] = gate2[t * 2 + 0];
  slot_tok[s1] = t; slot_gate[s1] = gate2[t * 2 + 1];
  tok_slot[t * 2 + 0] = s0;
  tok_slot[t * 2 + 1] = s1;
}

// ---------------- transpose-convert We[e][k][n] -> Wt[e][n][k] bf16 ----------------
__global__ __launch_bounds__(256) void wconv_kernel(const float* __restrict__ We,
                                                    unsigned short* __restrict__ Wt) {
  __shared__ float tile[64][65];
  int e = blockIdx.z;
  int k0 = blockIdx.x * 64, n0 = blockIdx.y * 64;
  int t = threadIdx.x;
  const float* src = We + ((size_t)e * HD + k0) * HD + n0;
#pragma unroll
  for (int i = 0; i < 4; i++) {
    int f = t + i * 256;
    int r = f >> 4, c4 = (f & 15) * 4;
    float4 v = *(const float4*)(src + (size_t)r * HD + c4);
    tile[r][c4 + 0] = v.x; tile[r][c4 + 1] = v.y;
    tile[r][c4 + 2] = v.z; tile[r][c4 + 3] = v.w;
  }
  __syncthreads();
  unsigned short* dst = Wt + ((size_t)e * HD + n0) * HD + k0;
#pragma unroll
  for (int i = 0; i < 2; i++) {
    int s = t + i * 256;
    int n = s >> 3, k8 = (s & 7) * 8;
    union { bf16x8 v; unsigned short us[8]; } o;
#pragma unroll
    for (int j = 0; j < 8; j++) o.us[j] = f2bf(tile[k8 + j][n]);
    *(bf16x8*)(dst + (size_t)n * HD + k8) = o.v;
  }
}

// ---------------- grouped GEMM: Y[slot] = bf16(A@We[e] + be[e]) (pre-gate) ----------------
#define BM 128
#define BN 128
#define BK 32
#define EPS 72   // epilogue LDS row stride in shorts (144B: 16B-aligned, low-conflict)

__global__ __launch_bounds__(256) void moe_gemm(
    const unsigned short* __restrict__ xbf, const unsigned short* __restrict__ Wt,
    const int* __restrict__ cnt, const int* __restrict__ slot_tok,
    const float* __restrict__ be, unsigned short* __restrict__ Ybf) {
  int bid = blockIdx.x;
  int e = bid >> 10;             // / (64*16)
  int rem = bid & 1023;
  int mt = rem >> 4, nt = rem & 15;
  int off = 0, c = 0;
#pragma unroll
  for (int i = 0; i < NE; i++) { int ci = cnt[i]; if (i < e) off += ci; if (i == e) c = ci; }
  if (mt * BM >= c) return;
  int row0 = off + mt * BM;      // base slot
  int n0 = nt * BN;

  __shared__ unsigned short Sm[BM * BK + BN * BK];  // 16 KB; reused by epilogue
  unsigned short* As = Sm;
  unsigned short* Bs = Sm + BM * BK;

  int tid = threadIdx.x;
  int lane = tid & 63, w = tid >> 6;
  int wm = w & 1, wn = w >> 1;
  int quad = lane >> 4, l16 = lane & 15;

  // staging: wave fills 32 A-rows + 32 B-rows; glds lane l -> (row=l>>2, 16B quarter=l&3)
  int srow = lane >> 2;
  int sq   = lane & 3;
  int ra0 = w * 32 + srow, ra1 = ra0 + 16;
  int sl0 = min(row0 + ra0, NSLOT - 1);   // clamp: last tile may overrun slot list
  int sl1 = min(row0 + ra1, NSLOT - 1);
  size_t ta0 = (size_t)slot_tok[sl0], ta1 = (size_t)slot_tok[sl1];
  const unsigned short* gA0 = xbf + ta0 * HD + sq * 8;
  const unsigned short* gA1 = xbf + ta1 * HD + sq * 8;
  const unsigned short* gB0 = Wt + ((size_t)e * HD + n0 + ra0) * HD + sq * 8;
  const unsigned short* gB1 = Wt + ((size_t)e * HD + n0 + ra1) * HD + sq * 8;
  unsigned short* lA0 = As + (w * 32) * BK;
  unsigned short* lA1 = As + (w * 32 + 16) * BK;
  unsigned short* lB0 = Bs + (w * 32) * BK;
  unsigned short* lB1 = Bs + (w * 32 + 16) * BK;

  const unsigned short* pa = As + (wm * 64 + l16) * BK + quad * 8;
  const unsigned short* pb = Bs + (wn * 64 + l16) * BK + quad * 8;

  f32x4 acc[4][4] = {};

  for (int k0 = 0; k0 < HD; k0 += BK) {
    GLDS16(gA0, lA0);
    GLDS16(gA1, lA1);
    GLDS16(gB0, lB0);
    GLDS16(gB1, lB1);
    gA0 += BK; gA1 += BK; gB0 += BK; gB1 += BK;
    __syncthreads();
    bf16x8 af[4], bfr[4];
#pragma unroll
    for (int i = 0; i < 4; i++) {
      af[i]  = *(const bf16x8*)(pa + i * 16 * BK);
      bfr[i] = *(const bf16x8*)(pb + i * 16 * BK);
    }
#pragma unroll
    for (int im = 0; im < 4; im++)
#pragma unroll
      for (int in = 0; in < 4; in++)
        acc[im][in] = __builtin_amdgcn_mfma_f32_16x16x32_bf16(af[im], bfr[in], acc[im][in], 0, 0, 0);
    __syncthreads();
  }

  // ---- epilogue: per-wave LDS transpose -> full-line coalesced Y stores ----
  float bias[4];
#pragma unroll
  for (int in = 0; in < 4; in++)
    bias[in] = be[e * HD + n0 + wn * 64 + in * 16 + l16];

  unsigned short* reg = Sm + w * (16 * EPS);   // 2.25 KB private region per wave
  int rrow = lane >> 2;            // 0..15 (read row within chunk)
  int rcol = (lane & 3) * 16;      // read col base (shorts)
#pragma unroll
  for (int im = 0; im < 4; im++) {
#pragma unroll
    for (int in = 0; in < 4; in++)
#pragma unroll
      for (int r = 0; r < 4; r++)
        reg[(quad * 4 + r) * EPS + in * 16 + l16] = f2bf(acc[im][in][r] + bias[in]);
    __syncthreads();
    int gr = mt * BM + wm * 64 + im * 16 + rrow;
    if (gr < c) {
      bf16x8 v0 = *(const bf16x8*)(reg + rrow * EPS + rcol);
      bf16x8 v1 = *(const bf16x8*)(reg + rrow * EPS + rcol + 8);
      unsigned short* dst = Ybf + (size_t)(off + gr) * HD + n0 + wn * 64 + rcol;
      *(bf16x8*)dst = v0;
      *(bf16x8*)(dst + 8) = v1;
    }
    __syncthreads();
  }
}

// ---------------- combine: out[t] = g0*Y[s0] + g1*Y[s1] ----------------
__global__ __launch_bounds__(256) void combine_kernel(
    const unsigned short* __restrict__ Ybf, const int* __restrict__ tok_slot,
    const float* __restrict__ slot_gate, float* __restrict__ out) {
  int c8 = threadIdx.x * 8;
#pragma unroll
  for (int i = 0; i < 4; i++) {
    int t = blockIdx.x * 4 + i;
    int s0 = tok_slot[t * 2], s1 = tok_slot[t * 2 + 1];
    float g0 = slot_gate[s0], g1 = slot_gate[s1];
    union { bf16x8 v; unsigned short s[8]; } y0, y1;
    y0.v = *(const bf16x8*)(Ybf + (size_t)s0 * HD + c8);
    y1.v = *(const bf16x8*)(Ybf + (size_t)s1 * HD + c8);
    float4 o0, o1;
    o0.x = g0 * bf2f(y0.s[0]) + g1 * bf2f(y1.s[0]);
    o0.y = g0 * bf2f(y0.s[1]) + g1 * bf2f(y1.s[1]);
    o0.z = g0 * bf2f(y0.s[2]) + g1 * bf2f(y1.s[2]);
    o0.w = g0 * bf2f(y0.s[3]) + g1 * bf2f(y1.s[3]);
    o1.x = g0 * bf2f(y0.s[4]) + g1 * bf2f(y1.s[4]);
    o1.y = g0 * bf2f(y0.s[5]) + g1 * bf2f(y1.s[5]);
    o1.z = g0 * bf2f(y0.s[6]) + g1 * bf2f(y1.s[6]);
    o1.w = g0 * bf2f(y0.s[7]) + g1 * bf2f(y1.s[7]);
    float4* dst = (float4*)(out + (size_t)t * HD + c8);
    dst[0] = o0;
    dst[1] = o1;
  }
}

extern "C" void kernel_launch(void* const* d_in, const int* in_sizes, int n_in,
                              void* d_out, int out_size, void* d_ws, size_t ws_size,
                              hipStream_t stream) {
  const float* x  = (const float*)d_in[0];
  const float* Wg = (const float*)d_in[1];
  const float* bg = (const float*)d_in[2];
  const float* We = (const float*)d_in[3];
  const float* be = (const float*)d_in[4];
  float* out = (float*)d_out;

  char* ws = (char*)d_ws;
  int* cnt        = (int*)ws;                          // 8 ints
  int* hist       = (int*)(ws + 256);                  // NCHUNK*NE ints (1 KB)
  int* chunk_base = (int*)(ws + 256 + 1024);           // NCHUNK*NE ints (1 KB)
  int* eidx2       = (int*)(ws + 4096);
  float* gate2     = (float*)(ws + 4096 + NSLOT * 4);
  int* slot_tok    = (int*)(ws + 4096 + 2 * NSLOT * 4);
  float* slot_gate = (float*)(ws + 4096 + 3 * NSLOT * 4);
  int* tok_slot    = (int*)(ws + 4096 + 4 * NSLOT * 4);
  unsigned short* xbf = (unsigned short*)(ws + 8192 + 5 * NSLOT * 4);  // TOK x HD bf16 (33.5 MB)
  unsigned short* Wt  = xbf + (size_t)TOK * HD;                        // E x HD x HD bf16 (67 MB)
  unsigned short* Ybf = Wt + (size_t)NE * HD * HD;                     // NSLOT x HD bf16 (67 MB)

  routex_kernel<<<TOK, 256, 0, stream>>>(x, Wg, bg, eidx2, gate2, xbf);
  hist_kernel<<<NCHUNK, 256, 0, stream>>>(eidx2, hist);
  scan_kernel<<<1, 64, 0, stream>>>(hist, cnt, chunk_base);
  assign_kernel<<<NCHUNK, 256, 0, stream>>>(eidx2, gate2, chunk_base, slot_tok, slot_gate, tok_slot);
  wconv_kernel<<<dim3(HD / 64, HD / 64, NE), 256, 0, stream>>>(We, Wt);
  moe_gemm<<<NE * 64 * 16, 256, 0, stream>>>(xbf, Wt, cnt, slot_tok, be, Ybf);
  combine_kernel<<<TOK / 4, 256, 0, stream>>>(Ybf, tok_slot, slot_gate, out);
}